// Round 3
// baseline (7199.863 us; speedup 1.0000x reference)
//
#include <hip/hip_runtime.h>
#include <hip/hip_bf16.h>

#define BB 2
#define SS 2048
#define DM 2048
#define NH 16
#define NKV 4
#define DH 128

typedef __hip_bfloat16 bf16;

__device__ __forceinline__ float tofl(float v) { return v; }
__device__ __forceinline__ float tofl(bf16 v) { return __bfloat162float(v); }
__device__ __forceinline__ void store_c(bf16* p, float v) { *p = __float2bfloat16(v); }
__device__ __forceinline__ void store_c(float* p, float v) { *p = v; }
__device__ __forceinline__ bf16 f2b(float v) { return __float2bfloat16(v); }

// ---------------- Tiled GEMM: C[M,N] = A[M,K] @ B[K,N], fp32 acc
// 64x64 tile, 256 threads, 4x4 per thread, K-tile 16.
template <typename TA, typename TB, typename TC>
__global__ __launch_bounds__(256) void gemm_k(const TA* __restrict__ A,
                                              const TB* __restrict__ Bm,
                                              TC* __restrict__ C,
                                              int M, int N, int K) {
    __shared__ float As[16][64];
    __shared__ float Bs[16][65];
    const int tid = threadIdx.x;
    const int tx = tid & 15, ty = tid >> 4;
    const int row0 = blockIdx.y * 64, col0 = blockIdx.x * 64;
    float acc[4][4] = {};
    for (int k0 = 0; k0 < K; k0 += 16) {
        #pragma unroll
        for (int i = tid; i < 1024; i += 256) {
            int r = i >> 4, kk = i & 15;
            As[kk][r] = tofl(A[(size_t)(row0 + r) * K + (k0 + kk)]);
        }
        #pragma unroll
        for (int i = tid; i < 1024; i += 256) {
            int kk = i >> 6, c = i & 63;
            Bs[kk][c] = tofl(Bm[(size_t)(k0 + kk) * N + (col0 + c)]);
        }
        __syncthreads();
        #pragma unroll
        for (int kk = 0; kk < 16; kk++) {
            float a[4], b[4];
            #pragma unroll
            for (int i = 0; i < 4; i++) a[i] = As[kk][ty * 4 + i];
            #pragma unroll
            for (int j = 0; j < 4; j++) b[j] = Bs[kk][tx * 4 + j];
            #pragma unroll
            for (int i = 0; i < 4; i++)
                #pragma unroll
                for (int j = 0; j < 4; j++)
                    acc[i][j] += a[i] * b[j];
        }
        __syncthreads();
    }
    #pragma unroll
    for (int i = 0; i < 4; i++)
        #pragma unroll
        for (int j = 0; j < 4; j++)
            store_c(&C[(size_t)(row0 + ty * 4 + i) * N + (col0 + tx * 4 + j)], acc[i][j]);
}

// ---------------- RoPE (interleaved pairs), in-place on bf16 tensor (B,S,nh,128)
__global__ void rope_kernel(bf16* __restrict__ t, const float* __restrict__ cs,
                            const float* __restrict__ sn, int n_heads, int total) {
    int idx = blockIdx.x * blockDim.x + threadIdx.x;
    if (idx >= total) return;
    int i = idx & 63;                          // pair index 0..63
    int h = (idx >> 6) % n_heads;
    size_t bs = (size_t)idx / (64 * n_heads);  // b*S + s
    int s = (int)(bs % SS);
    float c = cs[s * 64 + i];
    float si = sn[s * 64 + i];
    bf16* p = t + (bs * n_heads + h) * DH + 2 * i;
    float xr = tofl(p[0]), xi = tofl(p[1]);
    p[0] = f2b(xr * c - xi * si);
    p[1] = f2b(xr * si + xi * c);
}

// ---------------- Attention: one block per (b, h, query row). Causal.
__global__ __launch_bounds__(256) void attn_kernel(const bf16* __restrict__ q,
                                                   const bf16* __restrict__ k,
                                                   const bf16* __restrict__ v,
                                                   bf16* __restrict__ ao) {
    const int qs = blockIdx.x, h = blockIdx.y, b = blockIdx.z;
    const int kvh = h >> 2;  // n_rep = 4
    __shared__ float sc[SS];
    __shared__ float qv[DH];
    __shared__ float red[256];
    __shared__ float part[2][DH];
    const int tid = threadIdx.x;
    const bf16* qp = q + ((size_t)(b * SS + qs) * NH + h) * DH;
    if (tid < DH) qv[tid] = tofl(qp[tid]);
    __syncthreads();
    const int nk = qs + 1;
    const float scale = 0.08838834764831845f;  // 1/sqrt(128)

    for (int t = tid; t < nk; t += 256) {
        const bf16* kp = k + ((size_t)(b * SS + t) * NKV + kvh) * DH;
        float d = 0.f;
        #pragma unroll 8
        for (int j = 0; j < DH; j++) d += qv[j] * tofl(kp[j]);
        sc[t] = d * scale;
    }
    float m = -1e30f;
    for (int t = tid; t < nk; t += 256) m = fmaxf(m, sc[t]);
    red[tid] = m;
    __syncthreads();
    for (int off = 128; off > 0; off >>= 1) {
        if (tid < off) red[tid] = fmaxf(red[tid], red[tid + off]);
        __syncthreads();
    }
    m = red[0];
    __syncthreads();
    float lsum = 0.f;
    for (int t = tid; t < nk; t += 256) {
        float e = __expf(sc[t] - m);
        sc[t] = e;
        lsum += e;
    }
    red[tid] = lsum;
    __syncthreads();
    for (int off = 128; off > 0; off >>= 1) {
        if (tid < off) red[tid] += red[tid + off];
        __syncthreads();
    }
    const float inv = 1.f / red[0];
    __syncthreads();
    const int d = tid & 127, w = tid >> 7;
    float accp = 0.f;
    for (int t = w; t < nk; t += 2)
        accp += sc[t] * tofl(v[((size_t)(b * SS + t) * NKV + kvh) * DH + d]);
    part[w][d] = accp;
    __syncthreads();
    if (tid < DH)
        ao[((size_t)(b * SS + qs) * NH + h) * DH + tid] =
            f2b((part[0][tid] + part[1][tid]) * inv);
}

extern "C" void kernel_launch(void* const* d_in, const int* in_sizes, int n_in,
                              void* d_out, int out_size, void* d_ws, size_t ws_size,
                              hipStream_t stream) {
    const float* x  = (const float*)d_in[0];
    const float* fc = (const float*)d_in[1];
    const float* fs = (const float*)d_in[2];
    // d_in[3] = mask: exactly causal(0 / -1e9) -> implemented directly
    const float* wq = (const float*)d_in[4];
    const float* wk = (const float*)d_in[5];
    const float* wv = (const float*)d_in[6];
    const float* wo = (const float*)d_in[7];
    float* out = (float*)d_out;   // reference output dtype is fp32

    bf16* q  = (bf16*)d_ws;                    // B*S*NH*DH  = 8388608 elems
    bf16* k  = q + (size_t)BB * SS * NH * DH;  // B*S*NKV*DH = 2097152
    bf16* v  = k + (size_t)BB * SS * NKV * DH;
    bf16* ao = v + (size_t)BB * SS * NKV * DH; // 8388608

    const int M = BB * SS;  // 4096
    dim3 blk(256);
    gemm_k<float, float, bf16><<<dim3(DM / 64, M / 64), blk, 0, stream>>>(x, wq, q, M, NH * DH, DM);
    gemm_k<float, float, bf16><<<dim3((NKV * DH) / 64, M / 64), blk, 0, stream>>>(x, wk, k, M, NKV * DH, DM);
    gemm_k<float, float, bf16><<<dim3((NKV * DH) / 64, M / 64), blk, 0, stream>>>(x, wv, v, M, NKV * DH, DM);

    const int totq = BB * SS * NH * 64;
    const int totk = BB * SS * NKV * 64;
    rope_kernel<<<(totq + 255) / 256, blk, 0, stream>>>(q, fc, fs, NH, totq);
    rope_kernel<<<(totk + 255) / 256, blk, 0, stream>>>(k, fc, fs, NKV, totk);

    attn_kernel<<<dim3(SS, NH, BB), blk, 0, stream>>>(q, k, v, ao);

    gemm_k<bf16, float, float><<<dim3(DM / 64, M / 64), blk, 0, stream>>>(ao, wo, out, M, DM, DM);
}

// Round 5
// 2691.438 us; speedup vs baseline: 2.6751x; 2.6751x over previous
//
#include <hip/hip_runtime.h>
#include <hip/hip_bf16.h>

#define BB 2
#define SS 2048
#define DM 2048
#define NH 16
#define NKV 4
#define DH 128

typedef __hip_bfloat16 bf16;
typedef short short8 __attribute__((ext_vector_type(8)));
typedef float floatx4 __attribute__((ext_vector_type(4)));

__device__ __forceinline__ float tofl(float v) { return v; }
__device__ __forceinline__ float tofl(bf16 v) { return __bfloat162float(v); }
__device__ __forceinline__ void store_c(bf16* p, float v) { *p = __float2bfloat16(v); }
__device__ __forceinline__ void store_c(float* p, float v) { *p = v; }
__device__ __forceinline__ bf16 f2b(float v) { return __float2bfloat16(v); }
__device__ __forceinline__ short f2bs(float v) {
    bf16 t = __float2bfloat16(v);
    return __builtin_bit_cast(short, t);
}

// ---------------- Tiled GEMM: C[M,N] = A[M,K] @ B[K,N], fp32 acc
template <typename TA, typename TB, typename TC>
__global__ __launch_bounds__(256) void gemm_k(const TA* __restrict__ A,
                                              const TB* __restrict__ Bm,
                                              TC* __restrict__ C,
                                              int M, int N, int K) {
    __shared__ float As[16][64];
    __shared__ float Bs[16][65];
    const int tid = threadIdx.x;
    const int tx = tid & 15, ty = tid >> 4;
    const int row0 = blockIdx.y * 64, col0 = blockIdx.x * 64;
    float acc[4][4] = {};
    for (int k0 = 0; k0 < K; k0 += 16) {
        #pragma unroll
        for (int i = tid; i < 1024; i += 256) {
            int r = i >> 4, kk = i & 15;
            As[kk][r] = tofl(A[(size_t)(row0 + r) * K + (k0 + kk)]);
        }
        #pragma unroll
        for (int i = tid; i < 1024; i += 256) {
            int kk = i >> 6, c = i & 63;
            Bs[kk][c] = tofl(Bm[(size_t)(k0 + kk) * N + (col0 + c)]);
        }
        __syncthreads();
        #pragma unroll
        for (int kk = 0; kk < 16; kk++) {
            float a[4], b[4];
            #pragma unroll
            for (int i = 0; i < 4; i++) a[i] = As[kk][ty * 4 + i];
            #pragma unroll
            for (int j = 0; j < 4; j++) b[j] = Bs[kk][tx * 4 + j];
            #pragma unroll
            for (int i = 0; i < 4; i++)
                #pragma unroll
                for (int j = 0; j < 4; j++)
                    acc[i][j] += a[i] * b[j];
        }
        __syncthreads();
    }
    #pragma unroll
    for (int i = 0; i < 4; i++)
        #pragma unroll
        for (int j = 0; j < 4; j++)
            store_c(&C[(size_t)(row0 + ty * 4 + i) * N + (col0 + tx * 4 + j)], acc[i][j]);
}

// ---------------- RoPE (interleaved pairs), in-place on bf16 tensor (B,S,nh,128)
__global__ void rope_kernel(bf16* __restrict__ t, const float* __restrict__ cs,
                            const float* __restrict__ sn, int n_heads, int total) {
    int idx = blockIdx.x * blockDim.x + threadIdx.x;
    if (idx >= total) return;
    int i = idx & 63;
    int h = (idx >> 6) % n_heads;
    size_t bs = (size_t)idx / (64 * n_heads);
    int s = (int)(bs % SS);
    float c = cs[s * 64 + i];
    float si = sn[s * 64 + i];
    bf16* p = t + (bs * n_heads + h) * DH + 2 * i;
    float xr = tofl(p[0]), xi = tofl(p[1]);
    p[0] = f2b(xr * c - xi * si);
    p[1] = f2b(xr * si + xi * c);
}

// ---------------- V transpose: v[b][s][kvh][d] -> vt[b][kvh][d][s]
__global__ __launch_bounds__(256) void transpose_v(const bf16* __restrict__ v,
                                                   bf16* __restrict__ vt) {
    const int s0 = blockIdx.x * 64, d0 = blockIdx.y * 64;
    const int b = blockIdx.z >> 2, kvh = blockIdx.z & 3;
    __shared__ bf16 tile[64][65];
    const int tid = threadIdx.x;
    for (int i = tid; i < 4096; i += 256) {
        int r = i >> 6, c = i & 63;
        tile[r][c] = v[(((size_t)(b * SS + s0 + r)) * NKV + kvh) * DH + d0 + c];
    }
    __syncthreads();
    for (int i = tid; i < 4096; i += 256) {
        int r = i >> 6, c = i & 63;
        vt[(((size_t)(b * NKV + kvh)) * DH + d0 + r) * SS + s0 + c] = tile[c][r];
    }
}

// ---------------- Flash attention (causal, GQA), bf16 MFMA 16x16x32
// Grid (SS/64, NH, BB), 256 threads = 4 waves; wave w owns q rows q0+16w..+15.
#define KPAD 136  // 128+8 shorts
#define VPAD 72   // 64+8
#define PPAD 72

__global__ __launch_bounds__(256) void flash_attn(const bf16* __restrict__ q,
                                                  const bf16* __restrict__ kg,
                                                  const bf16* __restrict__ vt,
                                                  bf16* __restrict__ ao) {
    const int qt = blockIdx.x, h = blockIdx.y, b = blockIdx.z;
    const int q0 = qt * 64, kvh = h >> 2;
    __shared__ short Ks[64 * KPAD];        // [key][d]
    __shared__ short Vs[128 * VPAD];       // [d][key]
    __shared__ short Ps[4 * 16 * PPAD];    // per-wave [qrow][key]
    const int tid = threadIdx.x;
    const int w = tid >> 6, lane = tid & 63;
    const int col = lane & 15, quad = lane >> 4;

    // Q fragments (A-layout): row = q0+16w+col, chunk kc covers d = 32kc+8quad..+7
    short8 aq[4];
    const bf16* qbase = q + (((size_t)(b * SS + q0 + w * 16 + col)) * NH + h) * DH;
    #pragma unroll
    for (int kc = 0; kc < 4; kc++)
        aq[kc] = *(const short8*)(qbase + kc * 32 + quad * 8);

    floatx4 o[8];
    #pragma unroll
    for (int dt = 0; dt < 8; dt++) o[dt] = (floatx4){0.f, 0.f, 0.f, 0.f};
    float mrow[4] = {-3e38f, -3e38f, -3e38f, -3e38f};
    float lrow[4] = {0.f, 0.f, 0.f, 0.f};
    const float scale = 0.08838834764831845f;  // 1/sqrt(128)

    for (int kt = 0; kt <= qt; kt++) {
        const int k0 = kt * 64;
        __syncthreads();  // prior tile's LDS reads complete before restage
        // stage K tile [64 keys][128 d]: 1024 short8 chunks
        #pragma unroll
        for (int it = 0; it < 4; it++) {
            int i = tid + it * 256;
            int rr = i >> 4, seg = i & 15;
            short8 val = *(const short8*)(kg + (((size_t)(b * SS + k0 + rr)) * NKV + kvh) * DH + seg * 8);
            *(short8*)&Ks[rr * KPAD + seg * 8] = val;
        }
        // stage V^T tile [128 d][64 keys]: 1024 short8 chunks
        #pragma unroll
        for (int it = 0; it < 4; it++) {
            int i = tid + it * 256;
            int dd = i >> 3, sg = i & 7;
            short8 val = *(const short8*)(vt + (((size_t)(b * NKV + kvh)) * DH + dd) * SS + k0 + sg * 8);
            *(short8*)&Vs[dd * VPAD + sg * 8] = val;
        }
        __syncthreads();

        // S = Q K^T  (4 n-subtiles of 16 keys)
        floatx4 s[4];
        #pragma unroll
        for (int n = 0; n < 4; n++) {
            s[n] = (floatx4){0.f, 0.f, 0.f, 0.f};
            #pragma unroll
            for (int kc = 0; kc < 4; kc++) {
                short8 bk = *(const short8*)&Ks[(n * 16 + col) * KPAD + kc * 32 + quad * 8];
                s[n] = __builtin_amdgcn_mfma_f32_16x16x32_bf16(aq[kc], bk, s[n], 0, 0, 0);
            }
        }
        // scale + causal mask (diagonal tile only)
        #pragma unroll
        for (int n = 0; n < 4; n++)
            #pragma unroll
            for (int r = 0; r < 4; r++) {
                float v = s[n][r] * scale;
                if (kt == qt && (k0 + n * 16 + col) > (q0 + w * 16 + quad * 4 + r)) v = -3e38f;
                s[n][r] = v;
            }
        // online softmax per row (row = 4*quad + r; reduce over 16 lanes of quad)
        float alpha[4];
        #pragma unroll
        for (int r = 0; r < 4; r++) {
            float rm = fmaxf(fmaxf(s[0][r], s[1][r]), fmaxf(s[2][r], s[3][r]));
            rm = fmaxf(rm, __shfl_xor(rm, 1));
            rm = fmaxf(rm, __shfl_xor(rm, 2));
            rm = fmaxf(rm, __shfl_xor(rm, 4));
            rm = fmaxf(rm, __shfl_xor(rm, 8));
            float mn = fmaxf(mrow[r], rm);
            alpha[r] = __expf(mrow[r] - mn);
            mrow[r] = mn;
            float rs = 0.f;
            #pragma unroll
            for (int n = 0; n < 4; n++) {
                float p = __expf(s[n][r] - mn);
                s[n][r] = p;
                rs += p;
            }
            rs += __shfl_xor(rs, 1);
            rs += __shfl_xor(rs, 2);
            rs += __shfl_xor(rs, 4);
            rs += __shfl_xor(rs, 8);
            lrow[r] = lrow[r] * alpha[r] + rs;
        }
        // P (C-layout) -> LDS -> A-layout
        short* pw = &Ps[w * 16 * PPAD];
        #pragma unroll
        for (int n = 0; n < 4; n++)
            #pragma unroll
            for (int r = 0; r < 4; r++)
                pw[(quad * 4 + r) * PPAD + n * 16 + col] = f2bs(s[n][r]);
        // rescale O
        #pragma unroll
        for (int dt = 0; dt < 8; dt++)
            #pragma unroll
            for (int r = 0; r < 4; r++) o[dt][r] *= alpha[r];
        // O += P V   (8 d-subtiles, 2 key-chunks of 32)
        short8 ap0 = *(const short8*)&pw[col * PPAD + quad * 8];
        short8 ap1 = *(const short8*)&pw[col * PPAD + 32 + quad * 8];
        #pragma unroll
        for (int dt = 0; dt < 8; dt++) {
            short8 bv0 = *(const short8*)&Vs[(dt * 16 + col) * VPAD + quad * 8];
            o[dt] = __builtin_amdgcn_mfma_f32_16x16x32_bf16(ap0, bv0, o[dt], 0, 0, 0);
            short8 bv1 = *(const short8*)&Vs[(dt * 16 + col) * VPAD + 32 + quad * 8];
            o[dt] = __builtin_amdgcn_mfma_f32_16x16x32_bf16(ap1, bv1, o[dt], 0, 0, 0);
        }
    }
    // epilogue: O/l -> ao[b][s][h][d]
    #pragma unroll
    for (int r = 0; r < 4; r++) {
        float inv = 1.f / lrow[r];
        int srow = q0 + w * 16 + quad * 4 + r;
        bf16* op = ao + (((size_t)(b * SS + srow)) * NH + h) * DH;
        #pragma unroll
        for (int dt = 0; dt < 8; dt++)
            op[dt * 16 + col] = f2b(o[dt][r] * inv);
    }
}

extern "C" void kernel_launch(void* const* d_in, const int* in_sizes, int n_in,
                              void* d_out, int out_size, void* d_ws, size_t ws_size,
                              hipStream_t stream) {
    const float* x  = (const float*)d_in[0];
    const float* fc = (const float*)d_in[1];
    const float* fs = (const float*)d_in[2];
    // d_in[3] = mask: exactly causal(0 / -1e9) -> implemented directly
    const float* wq = (const float*)d_in[4];
    const float* wk = (const float*)d_in[5];
    const float* wv = (const float*)d_in[6];
    const float* wo = (const float*)d_in[7];
    float* out = (float*)d_out;

    bf16* q  = (bf16*)d_ws;                     // 8388608 elems
    bf16* k  = q + (size_t)BB * SS * NH * DH;   // 2097152
    bf16* v  = k + (size_t)BB * SS * NKV * DH;  // 2097152
    bf16* ao = v + (size_t)BB * SS * NKV * DH;  // 8388608
    bf16* vt = ao + (size_t)BB * SS * NH * DH;  // 2097152

    const int M = BB * SS;  // 4096
    dim3 blk(256);
    gemm_k<float, float, bf16><<<dim3(DM / 64, M / 64), blk, 0, stream>>>(x, wq, q, M, NH * DH, DM);
    gemm_k<float, float, bf16><<<dim3((NKV * DH) / 64, M / 64), blk, 0, stream>>>(x, wk, k, M, NKV * DH, DM);
    gemm_k<float, float, bf16><<<dim3((NKV * DH) / 64, M / 64), blk, 0, stream>>>(x, wv, v, M, NKV * DH, DM);

    const int totq = BB * SS * NH * 64;
    const int totk = BB * SS * NKV * 64;
    rope_kernel<<<(totq + 255) / 256, blk, 0, stream>>>(q, fc, fs, NH, totq);
    rope_kernel<<<(totk + 255) / 256, blk, 0, stream>>>(k, fc, fs, NKV, totk);

    transpose_v<<<dim3(SS / 64, DH / 64, BB * NKV), blk, 0, stream>>>(v, vt);

    flash_attn<<<dim3(SS / 64, NH, BB), blk, 0, stream>>>(q, k, vt, ao);

    gemm_k<bf16, float, float><<<dim3(DM / 64, M / 64), blk, 0, stream>>>(ao, wo, out, M, DM, DM);
}

// Round 6
// 463.439 us; speedup vs baseline: 15.5357x; 5.8075x over previous
//
#include <hip/hip_runtime.h>
#include <hip/hip_bf16.h>

#define BB 2
#define SS 2048
#define DM 2048
#define NH 16
#define NKV 4
#define DH 128
#define QS 3072   // packed qkv row stride: 2048 q | 512 k | 512 v

typedef __hip_bfloat16 bf16;
typedef short short8 __attribute__((ext_vector_type(8)));
typedef float floatx4 __attribute__((ext_vector_type(4)));

__device__ __forceinline__ bf16 f2b(float v) { return __float2bfloat16(v); }
__device__ __forceinline__ short f2bs(float v) {
    bf16 t = __float2bfloat16(v);
    return __builtin_bit_cast(short, t);
}
__device__ __forceinline__ void store_c(bf16* p, float v) { *p = __float2bfloat16(v); }
__device__ __forceinline__ void store_c(float* p, float v) { *p = v; }

// ---------------- x fp32 -> bf16 (vectorized)
__global__ __launch_bounds__(256) void convert_x(const float4* __restrict__ x,
                                                 bf16* __restrict__ xb, int n4) {
    int i = blockIdx.x * blockDim.x + threadIdx.x;
    if (i >= n4) return;
    float4 v = x[i];
    bf16* p = xb + (size_t)i * 4;
    p[0] = f2b(v.x); p[1] = f2b(v.y); p[2] = f2b(v.z); p[3] = f2b(v.w);
}

// ---------------- weight fp32 [Kd][N] -> bf16 transposed [N][Kd]
__global__ __launch_bounds__(256) void convert_wT(const float* __restrict__ w,
                                                  bf16* __restrict__ outT,
                                                  int N, int Kd) {
    const int n0 = blockIdx.x * 64, k0 = blockIdx.y * 64;
    __shared__ float tile[64][65];
    const int tid = threadIdx.x;
    for (int i = tid; i < 4096; i += 256) {
        int r = i >> 6, c = i & 63;  // r: k-local, c: n-local
        tile[r][c] = w[(size_t)(k0 + r) * N + n0 + c];
    }
    __syncthreads();
    for (int i = tid; i < 4096; i += 256) {
        int r = i >> 6, c = i & 63;  // r: n-local, c: k-local
        outT[(size_t)(n0 + r) * Kd + k0 + c] = f2b(tile[c][r]);
    }
}

// ---------------- MFMA GEMM: C[M,N] = A[M,K] @ BT[N,K]^T, bf16 in, fp32 acc
// 128x128 tile, BK=32, 4 waves (2x2 of 64x64), 16x16x32 bf16 MFMA.
// Staging: global_load_lds width=16, unpadded [row][32] LDS (row stride 64B
// = 16 banks => b128 frag reads hit the 8-access/bank floor, conflict-free).
template <typename TC>
__global__ __launch_bounds__(256) void mfma_gemm(const bf16* __restrict__ A,
                                                 const bf16* __restrict__ BT,
                                                 TC* __restrict__ C,
                                                 int M, int N, int K) {
    __shared__ short As[128 * 32];
    __shared__ short Bs[128 * 32];
    const int tid = threadIdx.x;
    const int w = tid >> 6, lane = tid & 63;
    const int col16 = lane & 15, quad = lane >> 4;
    const int row0 = blockIdx.y * 128, col0 = blockIdx.x * 128;
    const int wr0 = (w >> 1) * 64, wc0 = (w & 1) * 64;

    floatx4 acc[4][4];
    #pragma unroll
    for (int mi = 0; mi < 4; mi++)
        #pragma unroll
        for (int ni = 0; ni < 4; ni++) acc[mi][ni] = (floatx4){0.f, 0.f, 0.f, 0.f};

    for (int k0 = 0; k0 < K; k0 += 32) {
        __syncthreads();  // prior iter's LDS reads complete before restage
        #pragma unroll
        for (int it = 0; it < 2; it++) {
            int c = w * 128 + it * 64 + lane;       // chunk id 0..511
            int r = c >> 2, seg = c & 3;
            const bf16* g = A + (size_t)(row0 + r) * K + k0 + seg * 8;
            __builtin_amdgcn_global_load_lds(
                (const __attribute__((address_space(1))) unsigned int*)g,
                (__attribute__((address_space(3))) unsigned int*)&As[(w * 128 + it * 64) * 8],
                16, 0, 0);
        }
        #pragma unroll
        for (int it = 0; it < 2; it++) {
            int c = w * 128 + it * 64 + lane;
            int r = c >> 2, seg = c & 3;
            const bf16* g = BT + (size_t)(col0 + r) * K + k0 + seg * 8;
            __builtin_amdgcn_global_load_lds(
                (const __attribute__((address_space(1))) unsigned int*)g,
                (__attribute__((address_space(3))) unsigned int*)&Bs[(w * 128 + it * 64) * 8],
                16, 0, 0);
        }
        __syncthreads();

        short8 af[4], bfr[4];
        #pragma unroll
        for (int mi = 0; mi < 4; mi++)
            af[mi] = *(const short8*)&As[(wr0 + mi * 16 + col16) * 32 + quad * 8];
        #pragma unroll
        for (int ni = 0; ni < 4; ni++)
            bfr[ni] = *(const short8*)&Bs[(wc0 + ni * 16 + col16) * 32 + quad * 8];
        #pragma unroll
        for (int mi = 0; mi < 4; mi++)
            #pragma unroll
            for (int ni = 0; ni < 4; ni++)
                acc[mi][ni] = __builtin_amdgcn_mfma_f32_16x16x32_bf16(af[mi], bfr[ni], acc[mi][ni], 0, 0, 0);
    }
    // epilogue: C/D layout col=lane&15, row=quad*4+reg
    #pragma unroll
    for (int mi = 0; mi < 4; mi++)
        #pragma unroll
        for (int ni = 0; ni < 4; ni++)
            #pragma unroll
            for (int r = 0; r < 4; r++)
                store_c(&C[(size_t)(row0 + wr0 + mi * 16 + quad * 4 + r) * N +
                           col0 + wc0 + ni * 16 + col16],
                        acc[mi][ni][r]);
}

// ---------------- RoPE (interleaved pairs) on packed qkv
__global__ void rope_kernel(bf16* __restrict__ base, const float* __restrict__ cs,
                            const float* __restrict__ sn, int n_heads, int total) {
    int idx = blockIdx.x * blockDim.x + threadIdx.x;
    if (idx >= total) return;
    int i = idx & 63;
    int h = (idx >> 6) % n_heads;
    size_t bs = (size_t)idx / (64 * n_heads);
    int s = (int)(bs % SS);
    float c = cs[s * 64 + i];
    float si = sn[s * 64 + i];
    bf16* p = base + bs * QS + h * DH + 2 * i;
    float xr = __bfloat162float(p[0]), xi = __bfloat162float(p[1]);
    p[0] = f2b(xr * c - xi * si);
    p[1] = f2b(xr * si + xi * c);
}

// ---------------- V transpose: qkv packed v -> vt[b][kvh][d][s]
__global__ __launch_bounds__(256) void transpose_v(const bf16* __restrict__ qkv,
                                                   bf16* __restrict__ vt) {
    const int s0 = blockIdx.x * 64, d0 = blockIdx.y * 64;
    const int b = blockIdx.z >> 2, kvh = blockIdx.z & 3;
    __shared__ bf16 tile[64][65];
    const int tid = threadIdx.x;
    for (int i = tid; i < 4096; i += 256) {
        int r = i >> 6, c = i & 63;
        tile[r][c] = qkv[(size_t)(b * SS + s0 + r) * QS + 2560 + kvh * DH + d0 + c];
    }
    __syncthreads();
    for (int i = tid; i < 4096; i += 256) {
        int r = i >> 6, c = i & 63;
        vt[((size_t)(b * NKV + kvh) * DH + d0 + r) * SS + s0 + c] = tile[c][r];
    }
}

// ---------------- Flash attention (causal, GQA), bf16 MFMA 16x16x32
#define KPAD 136
#define VPAD 72
#define PPAD 72

__global__ __launch_bounds__(256) void flash_attn(const bf16* __restrict__ qkv,
                                                  const bf16* __restrict__ vt,
                                                  bf16* __restrict__ ao) {
    const int qt = blockIdx.x, h = blockIdx.y, b = blockIdx.z;
    const int q0 = qt * 64, kvh = h >> 2;
    __shared__ short Ks[64 * KPAD];
    __shared__ short Vs[128 * VPAD];
    __shared__ short Ps[4 * 16 * PPAD];
    const int tid = threadIdx.x;
    const int w = tid >> 6, lane = tid & 63;
    const int col = lane & 15, quad = lane >> 4;

    short8 aq[4];
    const bf16* qbase = qkv + (size_t)(b * SS + q0 + w * 16 + col) * QS + h * DH;
    #pragma unroll
    for (int kc = 0; kc < 4; kc++)
        aq[kc] = *(const short8*)(qbase + kc * 32 + quad * 8);

    floatx4 o[8];
    #pragma unroll
    for (int dt = 0; dt < 8; dt++) o[dt] = (floatx4){0.f, 0.f, 0.f, 0.f};
    float mrow[4] = {-3e38f, -3e38f, -3e38f, -3e38f};
    float lrow[4] = {0.f, 0.f, 0.f, 0.f};
    const float scale = 0.08838834764831845f;

    for (int kt = 0; kt <= qt; kt++) {
        const int k0 = kt * 64;
        __syncthreads();
        #pragma unroll
        for (int it = 0; it < 4; it++) {
            int i = tid + it * 256;
            int rr = i >> 4, seg = i & 15;
            short8 val = *(const short8*)(qkv + (size_t)(b * SS + k0 + rr) * QS + 2048 + kvh * DH + seg * 8);
            *(short8*)&Ks[rr * KPAD + seg * 8] = val;
        }
        #pragma unroll
        for (int it = 0; it < 4; it++) {
            int i = tid + it * 256;
            int dd = i >> 3, sg = i & 7;
            short8 val = *(const short8*)(vt + ((size_t)(b * NKV + kvh) * DH + dd) * SS + k0 + sg * 8);
            *(short8*)&Vs[dd * VPAD + sg * 8] = val;
        }
        __syncthreads();

        floatx4 s[4];
        #pragma unroll
        for (int n = 0; n < 4; n++) {
            s[n] = (floatx4){0.f, 0.f, 0.f, 0.f};
            #pragma unroll
            for (int kc = 0; kc < 4; kc++) {
                short8 bk = *(const short8*)&Ks[(n * 16 + col) * KPAD + kc * 32 + quad * 8];
                s[n] = __builtin_amdgcn_mfma_f32_16x16x32_bf16(aq[kc], bk, s[n], 0, 0, 0);
            }
        }
        #pragma unroll
        for (int n = 0; n < 4; n++)
            #pragma unroll
            for (int r = 0; r < 4; r++) {
                float v = s[n][r] * scale;
                if (kt == qt && (k0 + n * 16 + col) > (q0 + w * 16 + quad * 4 + r)) v = -3e38f;
                s[n][r] = v;
            }
        float alpha[4];
        #pragma unroll
        for (int r = 0; r < 4; r++) {
            float rm = fmaxf(fmaxf(s[0][r], s[1][r]), fmaxf(s[2][r], s[3][r]));
            rm = fmaxf(rm, __shfl_xor(rm, 1));
            rm = fmaxf(rm, __shfl_xor(rm, 2));
            rm = fmaxf(rm, __shfl_xor(rm, 4));
            rm = fmaxf(rm, __shfl_xor(rm, 8));
            float mn = fmaxf(mrow[r], rm);
            alpha[r] = __expf(mrow[r] - mn);
            mrow[r] = mn;
            float rs = 0.f;
            #pragma unroll
            for (int n = 0; n < 4; n++) {
                float p = __expf(s[n][r] - mn);
                s[n][r] = p;
                rs += p;
            }
            rs += __shfl_xor(rs, 1);
            rs += __shfl_xor(rs, 2);
            rs += __shfl_xor(rs, 4);
            rs += __shfl_xor(rs, 8);
            lrow[r] = lrow[r] * alpha[r] + rs;
        }
        short* pw = &Ps[w * 16 * PPAD];
        #pragma unroll
        for (int n = 0; n < 4; n++)
            #pragma unroll
            for (int r = 0; r < 4; r++)
                pw[(quad * 4 + r) * PPAD + n * 16 + col] = f2bs(s[n][r]);
        #pragma unroll
        for (int dt = 0; dt < 8; dt++)
            #pragma unroll
            for (int r = 0; r < 4; r++) o[dt][r] *= alpha[r];
        short8 ap0 = *(const short8*)&pw[col * PPAD + quad * 8];
        short8 ap1 = *(const short8*)&pw[col * PPAD + 32 + quad * 8];
        #pragma unroll
        for (int dt = 0; dt < 8; dt++) {
            short8 bv0 = *(const short8*)&Vs[(dt * 16 + col) * VPAD + quad * 8];
            o[dt] = __builtin_amdgcn_mfma_f32_16x16x32_bf16(ap0, bv0, o[dt], 0, 0, 0);
            short8 bv1 = *(const short8*)&Vs[(dt * 16 + col) * VPAD + 32 + quad * 8];
            o[dt] = __builtin_amdgcn_mfma_f32_16x16x32_bf16(ap1, bv1, o[dt], 0, 0, 0);
        }
    }
    #pragma unroll
    for (int r = 0; r < 4; r++) {
        float inv = 1.f / lrow[r];
        int srow = q0 + w * 16 + quad * 4 + r;
        bf16* op = ao + ((size_t)(b * SS + srow) * NH + h) * DH;
        #pragma unroll
        for (int dt = 0; dt < 8; dt++)
            op[dt * 16 + col] = f2b(o[dt][r] * inv);
    }
}

extern "C" void kernel_launch(void* const* d_in, const int* in_sizes, int n_in,
                              void* d_out, int out_size, void* d_ws, size_t ws_size,
                              hipStream_t stream) {
    const float* x  = (const float*)d_in[0];
    const float* fc = (const float*)d_in[1];
    const float* fs = (const float*)d_in[2];
    // d_in[3] = mask: exactly causal -> implemented directly
    const float* wq = (const float*)d_in[4];
    const float* wk = (const float*)d_in[5];
    const float* wv = (const float*)d_in[6];
    const float* wo = (const float*)d_in[7];
    float* out = (float*)d_out;

    const int M = BB * SS;  // 4096
    // workspace layout (bf16 elems), with lifetime-based aliasing:
    bf16* qkv    = (bf16*)d_ws;               // [0, 12582912)
    bf16* xb     = qkv + (size_t)M * QS;      // [12582912, 20971520)  (ao aliases later)
    bf16* wqkvT  = xb + (size_t)M * DM;       // [20971520, 27262976)  (vt aliases later)
    bf16* ao     = xb;                        // alias: xb dead after qkv GEMM
    bf16* vt     = wqkvT;                     // alias: wqkvT dead after qkv GEMM
    bf16* woT    = qkv;                       // alias: qkv dead after flash

    dim3 blk(256);
    convert_x<<<(M * DM / 4 + 255) / 256, blk, 0, stream>>>((const float4*)x, xb, M * DM / 4);
    convert_wT<<<dim3(DM / 64, DM / 64), blk, 0, stream>>>(wq, wqkvT, DM, DM);
    convert_wT<<<dim3((NKV * DH) / 64, DM / 64), blk, 0, stream>>>(wk, wqkvT + (size_t)2048 * DM, NKV * DH, DM);
    convert_wT<<<dim3((NKV * DH) / 64, DM / 64), blk, 0, stream>>>(wv, wqkvT + (size_t)2560 * DM, NKV * DH, DM);

    mfma_gemm<bf16><<<dim3(QS / 128, M / 128), blk, 0, stream>>>(xb, wqkvT, qkv, M, QS, DM);

    const int totq = BB * SS * NH * 64;
    const int totk = BB * SS * NKV * 64;
    rope_kernel<<<(totq + 255) / 256, blk, 0, stream>>>(qkv, fc, fs, NH, totq);
    rope_kernel<<<(totk + 255) / 256, blk, 0, stream>>>(qkv + 2048, fc, fs, NKV, totk);

    transpose_v<<<dim3(SS / 64, DH / 64, BB * NKV), blk, 0, stream>>>(qkv, vt);

    flash_attn<<<dim3(SS / 64, NH, BB), blk, 0, stream>>>(qkv, vt, ao);

    convert_wT<<<dim3(DM / 64, DM / 64), blk, 0, stream>>>(wo, woT, DM, DM);
    mfma_gemm<float><<<dim3(DM / 128, M / 128), blk, 0, stream>>>(ao, woT, out, M, DM, DM);
}

// Round 7
// 423.541 us; speedup vs baseline: 16.9992x; 1.0942x over previous
//
#include <hip/hip_runtime.h>
#include <hip/hip_bf16.h>

#define BB 2
#define SS 2048
#define DM 2048
#define NH 16
#define NKV 4
#define DH 128
#define QS 3072   // packed qkv row stride: 2048 q | 512 k | 512 v

typedef __hip_bfloat16 bf16;
typedef short short8 __attribute__((ext_vector_type(8)));
typedef float floatx4 __attribute__((ext_vector_type(4)));

__device__ __forceinline__ bf16 f2b(float v) { return __float2bfloat16(v); }
__device__ __forceinline__ short f2bs(float v) {
    bf16 t = __float2bfloat16(v);
    return __builtin_bit_cast(short, t);
}
__device__ __forceinline__ void store_c(bf16* p, float v) { *p = __float2bfloat16(v); }
__device__ __forceinline__ void store_c(float* p, float v) { *p = v; }

// ---------------- x fp32 -> bf16 (vectorized)
__global__ __launch_bounds__(256) void convert_x(const float4* __restrict__ x,
                                                 bf16* __restrict__ xb, int n4) {
    int i = blockIdx.x * blockDim.x + threadIdx.x;
    if (i >= n4) return;
    float4 v = x[i];
    bf16* p = xb + (size_t)i * 4;
    p[0] = f2b(v.x); p[1] = f2b(v.y); p[2] = f2b(v.z); p[3] = f2b(v.w);
}

// ---------------- weight fp32 [Kd][N] -> bf16 transposed [N][Kd]
__global__ __launch_bounds__(256) void convert_wT(const float* __restrict__ w,
                                                  bf16* __restrict__ outT,
                                                  int N, int Kd) {
    const int n0 = blockIdx.x * 64, k0 = blockIdx.y * 64;
    __shared__ float tile[64][65];
    const int tid = threadIdx.x;
    for (int i = tid; i < 4096; i += 256) {
        int r = i >> 6, c = i & 63;  // r: k-local, c: n-local
        tile[r][c] = w[(size_t)(k0 + r) * N + n0 + c];
    }
    __syncthreads();
    for (int i = tid; i < 4096; i += 256) {
        int r = i >> 6, c = i & 63;  // r: n-local, c: k-local
        outT[(size_t)(n0 + r) * Kd + k0 + c] = f2b(tile[c][r]);
    }
}

// ---------------- MFMA GEMM: C[M,N] = A[M,K] @ BT[N,K]^T, bf16 in, fp32 acc
// 128x128 tile, BK=32, 4 waves (2x2 of 64x64), 16x16x32 bf16 MFMA.
template <typename TC>
__global__ __launch_bounds__(256) void mfma_gemm(const bf16* __restrict__ A,
                                                 const bf16* __restrict__ BT,
                                                 TC* __restrict__ C,
                                                 int M, int N, int K) {
    __shared__ short As[128 * 32];
    __shared__ short Bs[128 * 32];
    const int tid = threadIdx.x;
    const int w = tid >> 6, lane = tid & 63;
    const int col16 = lane & 15, quad = lane >> 4;
    const int row0 = blockIdx.y * 128, col0 = blockIdx.x * 128;
    const int wr0 = (w >> 1) * 64, wc0 = (w & 1) * 64;

    floatx4 acc[4][4];
    #pragma unroll
    for (int mi = 0; mi < 4; mi++)
        #pragma unroll
        for (int ni = 0; ni < 4; ni++) acc[mi][ni] = (floatx4){0.f, 0.f, 0.f, 0.f};

    for (int k0 = 0; k0 < K; k0 += 32) {
        __syncthreads();
        #pragma unroll
        for (int it = 0; it < 2; it++) {
            int c = w * 128 + it * 64 + lane;
            int r = c >> 2, seg = c & 3;
            const bf16* g = A + (size_t)(row0 + r) * K + k0 + seg * 8;
            __builtin_amdgcn_global_load_lds(
                (const __attribute__((address_space(1))) unsigned int*)g,
                (__attribute__((address_space(3))) unsigned int*)&As[(w * 128 + it * 64) * 8],
                16, 0, 0);
        }
        #pragma unroll
        for (int it = 0; it < 2; it++) {
            int c = w * 128 + it * 64 + lane;
            int r = c >> 2, seg = c & 3;
            const bf16* g = BT + (size_t)(col0 + r) * K + k0 + seg * 8;
            __builtin_amdgcn_global_load_lds(
                (const __attribute__((address_space(1))) unsigned int*)g,
                (__attribute__((address_space(3))) unsigned int*)&Bs[(w * 128 + it * 64) * 8],
                16, 0, 0);
        }
        __syncthreads();

        short8 af[4], bfr[4];
        #pragma unroll
        for (int mi = 0; mi < 4; mi++)
            af[mi] = *(const short8*)&As[(wr0 + mi * 16 + col16) * 32 + quad * 8];
        #pragma unroll
        for (int ni = 0; ni < 4; ni++)
            bfr[ni] = *(const short8*)&Bs[(wc0 + ni * 16 + col16) * 32 + quad * 8];
        #pragma unroll
        for (int mi = 0; mi < 4; mi++)
            #pragma unroll
            for (int ni = 0; ni < 4; ni++)
                acc[mi][ni] = __builtin_amdgcn_mfma_f32_16x16x32_bf16(af[mi], bfr[ni], acc[mi][ni], 0, 0, 0);
    }
    #pragma unroll
    for (int mi = 0; mi < 4; mi++)
        #pragma unroll
        for (int ni = 0; ni < 4; ni++)
            #pragma unroll
            for (int r = 0; r < 4; r++)
                store_c(&C[(size_t)(row0 + wr0 + mi * 16 + quad * 4 + r) * N +
                           col0 + wc0 + ni * 16 + col16],
                        acc[mi][ni][r]);
}

// ---------------- RoPE (interleaved pairs) on packed qkv
__global__ void rope_kernel(bf16* __restrict__ base, const float* __restrict__ cs,
                            const float* __restrict__ sn, int n_heads, int total) {
    int idx = blockIdx.x * blockDim.x + threadIdx.x;
    if (idx >= total) return;
    int i = idx & 63;
    int h = (idx >> 6) % n_heads;
    size_t bs = (size_t)idx / (64 * n_heads);
    int s = (int)(bs % SS);
    float c = cs[s * 64 + i];
    float si = sn[s * 64 + i];
    bf16* p = base + bs * QS + h * DH + 2 * i;
    float xr = __bfloat162float(p[0]), xi = __bfloat162float(p[1]);
    p[0] = f2b(xr * c - xi * si);
    p[1] = f2b(xr * si + xi * c);
}

// ---------------- V transpose: qkv packed v -> vt[b][kvh][d][s]
__global__ __launch_bounds__(256) void transpose_v(const bf16* __restrict__ qkv,
                                                   bf16* __restrict__ vt) {
    const int s0 = blockIdx.x * 64, d0 = blockIdx.y * 64;
    const int b = blockIdx.z >> 2, kvh = blockIdx.z & 3;
    __shared__ bf16 tile[64][65];
    const int tid = threadIdx.x;
    for (int i = tid; i < 4096; i += 256) {
        int r = i >> 6, c = i & 63;
        tile[r][c] = qkv[(size_t)(b * SS + s0 + r) * QS + 2560 + kvh * DH + d0 + c];
    }
    __syncthreads();
    for (int i = tid; i < 4096; i += 256) {
        int r = i >> 6, c = i & 63;
        vt[((size_t)(b * NKV + kvh) * DH + d0 + r) * SS + s0 + c] = tile[c][r];
    }
}

// ---------------- Flash attention (causal, GQA), bf16 MFMA 16x16x32
// Causal load-balance pairing: block bx processes Q-tile bx, then Q-tile
// (SS/64-1)-bx  =>  every block does exactly (SS/64)+1 = 33 K-tile iters.
#define KPAD 136
#define VPAD 72
#define PPAD 72

__global__ __launch_bounds__(256) void flash_attn(const bf16* __restrict__ qkv,
                                                  const bf16* __restrict__ vt,
                                                  bf16* __restrict__ ao) {
    const int bx = blockIdx.x, h = blockIdx.y, b = blockIdx.z;
    const int kvh = h >> 2;
    __shared__ short Ks[64 * KPAD];
    __shared__ short Vs[128 * VPAD];
    __shared__ short Ps[4 * 16 * PPAD];
    const int tid = threadIdx.x;
    const int w = tid >> 6, lane = tid & 63;
    const int col = lane & 15, quad = lane >> 4;
    const float scale = 0.08838834764831845f;

    for (int phase = 0; phase < 2; phase++) {
        const int qt = phase == 0 ? bx : (SS / 64 - 1 - bx);
        const int q0 = qt * 64;

        short8 aq[4];
        const bf16* qbase = qkv + (size_t)(b * SS + q0 + w * 16 + col) * QS + h * DH;
        #pragma unroll
        for (int kc = 0; kc < 4; kc++)
            aq[kc] = *(const short8*)(qbase + kc * 32 + quad * 8);

        floatx4 o[8];
        #pragma unroll
        for (int dt = 0; dt < 8; dt++) o[dt] = (floatx4){0.f, 0.f, 0.f, 0.f};
        float mrow[4] = {-3e38f, -3e38f, -3e38f, -3e38f};
        float lrow[4] = {0.f, 0.f, 0.f, 0.f};

        for (int kt = 0; kt <= qt; kt++) {
            const int k0 = kt * 64;
            __syncthreads();  // prior tile's LDS reads complete before restage
            #pragma unroll
            for (int it = 0; it < 4; it++) {
                int i = tid + it * 256;
                int rr = i >> 4, seg = i & 15;
                short8 val = *(const short8*)(qkv + (size_t)(b * SS + k0 + rr) * QS + 2048 + kvh * DH + seg * 8);
                *(short8*)&Ks[rr * KPAD + seg * 8] = val;
            }
            #pragma unroll
            for (int it = 0; it < 4; it++) {
                int i = tid + it * 256;
                int dd = i >> 3, sg = i & 7;
                short8 val = *(const short8*)(vt + ((size_t)(b * NKV + kvh) * DH + dd) * SS + k0 + sg * 8);
                *(short8*)&Vs[dd * VPAD + sg * 8] = val;
            }
            __syncthreads();

            floatx4 s[4];
            #pragma unroll
            for (int n = 0; n < 4; n++) {
                s[n] = (floatx4){0.f, 0.f, 0.f, 0.f};
                #pragma unroll
                for (int kc = 0; kc < 4; kc++) {
                    short8 bk = *(const short8*)&Ks[(n * 16 + col) * KPAD + kc * 32 + quad * 8];
                    s[n] = __builtin_amdgcn_mfma_f32_16x16x32_bf16(aq[kc], bk, s[n], 0, 0, 0);
                }
            }
            #pragma unroll
            for (int n = 0; n < 4; n++)
                #pragma unroll
                for (int r = 0; r < 4; r++) {
                    float v = s[n][r] * scale;
                    if (kt == qt && (k0 + n * 16 + col) > (q0 + w * 16 + quad * 4 + r)) v = -3e38f;
                    s[n][r] = v;
                }
            float alpha[4];
            #pragma unroll
            for (int r = 0; r < 4; r++) {
                float rm = fmaxf(fmaxf(s[0][r], s[1][r]), fmaxf(s[2][r], s[3][r]));
                rm = fmaxf(rm, __shfl_xor(rm, 1));
                rm = fmaxf(rm, __shfl_xor(rm, 2));
                rm = fmaxf(rm, __shfl_xor(rm, 4));
                rm = fmaxf(rm, __shfl_xor(rm, 8));
                float mn = fmaxf(mrow[r], rm);
                alpha[r] = __expf(mrow[r] - mn);
                mrow[r] = mn;
                float rs = 0.f;
                #pragma unroll
                for (int n = 0; n < 4; n++) {
                    float p = __expf(s[n][r] - mn);
                    s[n][r] = p;
                    rs += p;
                }
                rs += __shfl_xor(rs, 1);
                rs += __shfl_xor(rs, 2);
                rs += __shfl_xor(rs, 4);
                rs += __shfl_xor(rs, 8);
                lrow[r] = lrow[r] * alpha[r] + rs;
            }
            short* pw = &Ps[w * 16 * PPAD];
            #pragma unroll
            for (int n = 0; n < 4; n++)
                #pragma unroll
                for (int r = 0; r < 4; r++)
                    pw[(quad * 4 + r) * PPAD + n * 16 + col] = f2bs(s[n][r]);
            #pragma unroll
            for (int dt = 0; dt < 8; dt++)
                #pragma unroll
                for (int r = 0; r < 4; r++) o[dt][r] *= alpha[r];
            short8 ap0 = *(const short8*)&pw[col * PPAD + quad * 8];
            short8 ap1 = *(const short8*)&pw[col * PPAD + 32 + quad * 8];
            #pragma unroll
            for (int dt = 0; dt < 8; dt++) {
                short8 bv0 = *(const short8*)&Vs[(dt * 16 + col) * VPAD + quad * 8];
                o[dt] = __builtin_amdgcn_mfma_f32_16x16x32_bf16(ap0, bv0, o[dt], 0, 0, 0);
                short8 bv1 = *(const short8*)&Vs[(dt * 16 + col) * VPAD + 32 + quad * 8];
                o[dt] = __builtin_amdgcn_mfma_f32_16x16x32_bf16(ap1, bv1, o[dt], 0, 0, 0);
            }
        }
        #pragma unroll
        for (int r = 0; r < 4; r++) {
            float inv = 1.f / lrow[r];
            int srow = q0 + w * 16 + quad * 4 + r;
            bf16* op = ao + ((size_t)(b * SS + srow) * NH + h) * DH;
            #pragma unroll
            for (int dt = 0; dt < 8; dt++)
                op[dt * 16 + col] = f2b(o[dt][r] * inv);
        }
    }
}

extern "C" void kernel_launch(void* const* d_in, const int* in_sizes, int n_in,
                              void* d_out, int out_size, void* d_ws, size_t ws_size,
                              hipStream_t stream) {
    const float* x  = (const float*)d_in[0];
    const float* fc = (const float*)d_in[1];
    const float* fs = (const float*)d_in[2];
    // d_in[3] = mask: exactly causal -> implemented directly
    const float* wq = (const float*)d_in[4];
    const float* wk = (const float*)d_in[5];
    const float* wv = (const float*)d_in[6];
    const float* wo = (const float*)d_in[7];
    float* out = (float*)d_out;

    const int M = BB * SS;  // 4096
    bf16* qkv    = (bf16*)d_ws;               // [0, 12582912)
    bf16* xb     = qkv + (size_t)M * QS;      // [12582912, 20971520)
    bf16* wqkvT  = xb + (size_t)M * DM;       // [20971520, 27262976)
    bf16* ao     = xb;                        // alias: xb dead after qkv GEMM
    bf16* vt     = wqkvT;                     // alias: wqkvT dead after qkv GEMM
    bf16* woT    = qkv;                       // alias: qkv dead after flash

    dim3 blk(256);
    convert_x<<<(M * DM / 4 + 255) / 256, blk, 0, stream>>>((const float4*)x, xb, M * DM / 4);
    convert_wT<<<dim3(DM / 64, DM / 64), blk, 0, stream>>>(wq, wqkvT, DM, DM);
    convert_wT<<<dim3((NKV * DH) / 64, DM / 64), blk, 0, stream>>>(wk, wqkvT + (size_t)2048 * DM, NKV * DH, DM);
    convert_wT<<<dim3((NKV * DH) / 64, DM / 64), blk, 0, stream>>>(wv, wqkvT + (size_t)2560 * DM, NKV * DH, DM);

    mfma_gemm<bf16><<<dim3(QS / 128, M / 128), blk, 0, stream>>>(xb, wqkvT, qkv, M, QS, DM);

    const int totq = BB * SS * NH * 64;
    const int totk = BB * SS * NKV * 64;
    rope_kernel<<<(totq + 255) / 256, blk, 0, stream>>>(qkv, fc, fs, NH, totq);
    rope_kernel<<<(totk + 255) / 256, blk, 0, stream>>>(qkv + 2048, fc, fs, NKV, totk);

    transpose_v<<<dim3(SS / 64, DH / 64, BB * NKV), blk, 0, stream>>>(qkv, vt);

    flash_attn<<<dim3(SS / 128, NH, BB), blk, 0, stream>>>(qkv, vt, ao);

    convert_wT<<<dim3(DM / 64, DM / 64), blk, 0, stream>>>(wo, woT, DM, DM);
    mfma_gemm<float><<<dim3(DM / 128, M / 128), blk, 0, stream>>>(ao, woT, out, M, DM, DM);
}